// Round 4
// baseline (83.883 us; speedup 1.0000x reference)
//
#include <hip/hip_runtime.h>

// Padded LDS layout: matrix m occupies float4 slots [m*5, m*5+3]; slot m*5+4 is pad.
// 256 matrices * 5 float4 = 1280 float4 = 20 KiB.
__device__ __forceinline__ int lds_slot(int p) {   // p = linear float4 row index
    return (p >> 2) * 5 + (p & 3);
}

__global__ __launch_bounds__(256) void se3_apply_lds_pad(
    const float* __restrict__ ext,   // [B,4,4]
    const float* __restrict__ se3,   // [N,6]
    const int*   __restrict__ idx,   // [B]
    float*       __restrict__ out,   // [B,4,4]
    int B)
{
    __shared__ float4 lds[1280];     // 20 KiB
    const int t = threadIdx.x;
    const size_t mbase = (size_t)blockIdx.x * 256;
    const int b  = (int)mbase + t;
    const int cb = (b < B) ? b : (B - 1);

    // ---- start the dependent gather chain FIRST ----
    int j = idx[cb];

    // ---- cooperative lane-contiguous staging of 256 ext matrices ----
    const float4* extv = reinterpret_cast<const float4*>(ext);
    const size_t fbase = mbase * 4;
    const size_t fmax  = (size_t)B * 4;
    size_t g0 = fbase + t;
    size_t g1 = fbase + t + 256;
    size_t g2 = fbase + t + 512;
    size_t g3 = fbase + t + 768;
    float4 s0 = extv[g0 < fmax ? g0 : 0];
    float4 s1 = extv[g1 < fmax ? g1 : 0];
    float4 s2 = extv[g2 < fmax ? g2 : 0];
    float4 s3 = extv[g3 < fmax ? g3 : 0];

    // ---- se3 row gather (overlaps the staging loads in flight) ----
    const float* w6 = se3 + (size_t)j * 6;
    float2 a0 = *reinterpret_cast<const float2*>(w6 + 0);
    float2 a1 = *reinterpret_cast<const float2*>(w6 + 2);
    float2 a2 = *reinterpret_cast<const float2*>(w6 + 4);

    lds[lds_slot(t      )] = s0;
    lds[lds_slot(t + 256)] = s1;
    lds[lds_slot(t + 512)] = s2;
    lds[lds_slot(t + 768)] = s3;
    __syncthreads();

    // ---- each thread reads its own matrix (stride-5: conflict-free) ----
    float4 e0 = lds[t*5 + 0];
    float4 e1 = lds[t*5 + 1];
    float4 e2 = lds[t*5 + 2];
    float4 e3 = lds[t*5 + 3];

    // ---- se3 exp map (reference semantics: clip(dot, EPS)) ----
    float tx = a0.x, ty = a0.y, tz = a1.x;
    float x  = a1.y, y  = a2.x, z  = a2.y;

    float dot   = x*x + y*y + z*z;
    float theta = sqrtf(fmaxf(dot, 1e-4f));
    float inv   = 1.0f / theta;
    float s, c;
    sincosf(theta, &s, &c);
    float A  = s * inv;
    float Bc = (1.0f - c) * inv * inv;
    float Cc = (theta - s) * inv * inv * inv;

    float xx = x*x, yy = y*y, zz = z*z;
    float xy = x*y, xz = x*z, yz = y*z;

    float R00 = 1.0f - Bc*(yy + zz);
    float R01 = -A*z + Bc*xy;
    float R02 =  A*y + Bc*xz;
    float R10 =  A*z + Bc*xy;
    float R11 = 1.0f - Bc*(xx + zz);
    float R12 = -A*x + Bc*yz;
    float R20 = -A*y + Bc*xz;
    float R21 =  A*x + Bc*yz;
    float R22 = 1.0f - Bc*(xx + yy);

    float V00 = 1.0f - Cc*(yy + zz);
    float V01 = -Bc*z + Cc*xy;
    float V02 =  Bc*y + Cc*xz;
    float V10 =  Bc*z + Cc*xy;
    float V11 = 1.0f - Cc*(xx + zz);
    float V12 = -Bc*x + Cc*yz;
    float V20 = -Bc*y + Cc*xz;
    float V21 =  Bc*x + Cc*yz;
    float V22 = 1.0f - Cc*(xx + yy);

    float T0 = V00*tx + V01*ty + V02*tz;
    float T1 = V10*tx + V11*ty + V12*tz;
    float T2 = V20*tx + V21*ty + V22*tz;

    float4 o0, o1, o2;
    o0.x = R00*e0.x + R01*e1.x + R02*e2.x + T0*e3.x;
    o0.y = R00*e0.y + R01*e1.y + R02*e2.y + T0*e3.y;
    o0.z = R00*e0.z + R01*e1.z + R02*e2.z + T0*e3.z;
    o0.w = R00*e0.w + R01*e1.w + R02*e2.w + T0*e3.w;

    o1.x = R10*e0.x + R11*e1.x + R12*e2.x + T1*e3.x;
    o1.y = R10*e0.y + R11*e1.y + R12*e2.y + T1*e3.y;
    o1.z = R10*e0.z + R11*e1.z + R12*e2.z + T1*e3.z;
    o1.w = R10*e0.w + R11*e1.w + R12*e2.w + T1*e3.w;

    o2.x = R20*e0.x + R21*e1.x + R22*e2.x + T2*e3.x;
    o2.y = R20*e0.y + R21*e1.y + R22*e2.y + T2*e3.y;
    o2.z = R20*e0.z + R21*e1.z + R22*e2.z + T2*e3.z;
    o2.w = R20*e0.w + R21*e1.w + R22*e2.w + T2*e3.w;

    // Thread t only overwrites its OWN matrix's slots (rows 0-2); row 3 stays
    // as staged ext row 3, which IS the correct output row 3. No barrier
    // needed between this thread's reads above and its writes here.
    lds[t*5 + 0] = o0;
    lds[t*5 + 1] = o1;
    lds[t*5 + 2] = o2;
    __syncthreads();

    // ---- cooperative lane-contiguous store ----
    float4* outv = reinterpret_cast<float4*>(out);
    if (g0 < fmax) outv[g0] = lds[lds_slot(t      )];
    if (g1 < fmax) outv[g1] = lds[lds_slot(t + 256)];
    if (g2 < fmax) outv[g2] = lds[lds_slot(t + 512)];
    if (g3 < fmax) outv[g3] = lds[lds_slot(t + 768)];
}

extern "C" void kernel_launch(void* const* d_in, const int* in_sizes, int n_in,
                              void* d_out, int out_size, void* d_ws, size_t ws_size,
                              hipStream_t stream) {
    const float* ext = (const float*)d_in[0];   // [B,4,4]
    const float* se3 = (const float*)d_in[1];   // [N,6]
    const int*   idx = (const int*)d_in[2];     // [B]
    float* out = (float*)d_out;

    int B = in_sizes[2];
    int block = 256;
    int grid = (B + 255) / 256;
    se3_apply_lds_pad<<<grid, block, 0, stream>>>(ext, se3, idx, out, B);
}

// Round 6
// 80.379 us; speedup vs baseline: 1.0436x; 1.0436x over previous
//
#include <hip/hip_runtime.h>

typedef float f32x4 __attribute__((ext_vector_type(4)));

// Padded LDS layout: matrix m occupies float4 slots [m*5, m*5+3]; slot m*5+4 is pad.
__device__ __forceinline__ int lds_slot(int p) {   // p = linear float4 row index
    return (p >> 2) * 5 + (p & 3);
}

__global__ __launch_bounds__(256) void se3_apply_g2(
    const float* __restrict__ ext,   // [B,4,4]
    const float* __restrict__ se3,   // [N,6]
    const int*   __restrict__ idx,   // [B]
    float*       __restrict__ out,   // [B,4,4]
    int B, int N)
{
    __shared__ f32x4 lds[1280];      // 20 KiB
    const int t = threadIdx.x;
    const size_t mbase = (size_t)blockIdx.x * 256;
    const int b  = (int)mbase + t;
    const int cb = (b < B) ? b : (B - 1);

    // ---- start the dependent gather chain FIRST ----
    int j = idx[cb];

    // ---- gather se3 row as TWO aligned float4s (branchless select) ----
    size_t byte  = (size_t)j * 24;
    size_t base  = byte & ~(size_t)15;
    size_t total = (size_t)N * 24;
    if (base + 32 > total) base = total - 32;   // clamp at table end (keeps delta in {0,8})
    const f32x4* sf = reinterpret_cast<const f32x4*>(
                          reinterpret_cast<const char*>(se3) + base);
    f32x4 q0 = sf[0];
    f32x4 q1 = sf[1];
    bool sh = (byte != base);        // 8-byte phase

    // ---- cooperative lane-contiguous staging of 256 ext matrices (nontemporal) ----
    const f32x4* extv = reinterpret_cast<const f32x4*>(ext);
    const size_t fbase = mbase * 4;
    const size_t fmax  = (size_t)B * 4;
    size_t g0 = fbase + t;
    size_t g1 = fbase + t + 256;
    size_t g2 = fbase + t + 512;
    size_t g3 = fbase + t + 768;
    f32x4 s0 = __builtin_nontemporal_load(&extv[g0 < fmax ? g0 : 0]);
    f32x4 s1 = __builtin_nontemporal_load(&extv[g1 < fmax ? g1 : 0]);
    f32x4 s2 = __builtin_nontemporal_load(&extv[g2 < fmax ? g2 : 0]);
    f32x4 s3 = __builtin_nontemporal_load(&extv[g3 < fmax ? g3 : 0]);

    lds[lds_slot(t      )] = s0;
    lds[lds_slot(t + 256)] = s1;
    lds[lds_slot(t + 512)] = s2;
    lds[lds_slot(t + 768)] = s3;
    __syncthreads();

    // ---- each thread reads its own matrix (stride-5: conflict-free) ----
    f32x4 e0 = lds[t*5 + 0];
    f32x4 e1 = lds[t*5 + 1];
    f32x4 e2 = lds[t*5 + 2];
    f32x4 e3 = lds[t*5 + 3];

    // ---- unpack gathered row ----
    float tx = sh ? q0.z : q0.x;
    float ty = sh ? q0.w : q0.y;
    float tz = sh ? q1.x : q0.z;
    float x  = sh ? q1.y : q0.w;
    float y  = sh ? q1.z : q1.x;
    float z  = sh ? q1.w : q1.y;

    // ---- se3 exp map (reference semantics: clip(dot, EPS)) ----
    float dot   = x*x + y*y + z*z;
    float t2    = fmaxf(dot, 1e-4f);
    float inv   = rsqrtf(t2);
    float theta = t2 * inv;          // sqrt(t2)
    float s = __sinf(theta);
    float c = __cosf(theta);
    float A  = s * inv;
    float Bc = (1.0f - c) * inv * inv;
    float Cc = (theta - s) * inv * inv * inv;

    float xx = x*x, yy = y*y, zz = z*z;
    float xy = x*y, xz = x*z, yz = y*z;

    float R00 = 1.0f - Bc*(yy + zz);
    float R01 = -A*z + Bc*xy;
    float R02 =  A*y + Bc*xz;
    float R10 =  A*z + Bc*xy;
    float R11 = 1.0f - Bc*(xx + zz);
    float R12 = -A*x + Bc*yz;
    float R20 = -A*y + Bc*xz;
    float R21 =  A*x + Bc*yz;
    float R22 = 1.0f - Bc*(xx + yy);

    float V00 = 1.0f - Cc*(yy + zz);
    float V01 = -Bc*z + Cc*xy;
    float V02 =  Bc*y + Cc*xz;
    float V10 =  Bc*z + Cc*xy;
    float V11 = 1.0f - Cc*(xx + zz);
    float V12 = -Bc*x + Cc*yz;
    float V20 = -Bc*y + Cc*xz;
    float V21 =  Bc*x + Cc*yz;
    float V22 = 1.0f - Cc*(xx + yy);

    float T0 = V00*tx + V01*ty + V02*tz;
    float T1 = V10*tx + V11*ty + V12*tz;
    float T2 = V20*tx + V21*ty + V22*tz;

    f32x4 o0, o1, o2;
    o0.x = R00*e0.x + R01*e1.x + R02*e2.x + T0*e3.x;
    o0.y = R00*e0.y + R01*e1.y + R02*e2.y + T0*e3.y;
    o0.z = R00*e0.z + R01*e1.z + R02*e2.z + T0*e3.z;
    o0.w = R00*e0.w + R01*e1.w + R02*e2.w + T0*e3.w;

    o1.x = R10*e0.x + R11*e1.x + R12*e2.x + T1*e3.x;
    o1.y = R10*e0.y + R11*e1.y + R12*e2.y + T1*e3.y;
    o1.z = R10*e0.z + R11*e1.z + R12*e2.z + T1*e3.z;
    o1.w = R10*e0.w + R11*e1.w + R12*e2.w + T1*e3.w;

    o2.x = R20*e0.x + R21*e1.x + R22*e2.x + T2*e3.x;
    o2.y = R20*e0.y + R21*e1.y + R22*e2.y + T2*e3.y;
    o2.z = R20*e0.z + R21*e1.z + R22*e2.z + T2*e3.z;
    o2.w = R20*e0.w + R21*e1.w + R22*e2.w + T2*e3.w;

    // Thread t only overwrites its OWN matrix's slots (rows 0-2); row 3 stays
    // as staged ext row 3, which IS the correct output row 3.
    lds[t*5 + 0] = o0;
    lds[t*5 + 1] = o1;
    lds[t*5 + 2] = o2;
    __syncthreads();

    // ---- cooperative lane-contiguous nontemporal store ----
    f32x4* outv = reinterpret_cast<f32x4*>(out);
    if (g0 < fmax) __builtin_nontemporal_store(lds[lds_slot(t      )], &outv[g0]);
    if (g1 < fmax) __builtin_nontemporal_store(lds[lds_slot(t + 256)], &outv[g1]);
    if (g2 < fmax) __builtin_nontemporal_store(lds[lds_slot(t + 512)], &outv[g2]);
    if (g3 < fmax) __builtin_nontemporal_store(lds[lds_slot(t + 768)], &outv[g3]);
}

extern "C" void kernel_launch(void* const* d_in, const int* in_sizes, int n_in,
                              void* d_out, int out_size, void* d_ws, size_t ws_size,
                              hipStream_t stream) {
    const float* ext = (const float*)d_in[0];   // [B,4,4]
    const float* se3 = (const float*)d_in[1];   // [N,6]
    const int*   idx = (const int*)d_in[2];     // [B]
    float* out = (float*)d_out;

    int B = in_sizes[2];
    int N = in_sizes[1] / 6;
    int block = 256;
    int grid = (B + 255) / 256;
    se3_apply_g2<<<grid, block, 0, stream>>>(ext, se3, idx, out, B, N);
}